// Round 2
// baseline (1436.940 us; speedup 1.0000x reference)
//
#include <hip/hip_runtime.h>

#define RES 512
#define NC 16
#define NPLANES 3

// ---------------------------------------------------------------------------
// Transpose planes [3][16][512][512] -> [3][512][512][16] (channel innermost)
// so a bilinear texel fetch of 16 channels is one contiguous 64B line.
// ---------------------------------------------------------------------------
__global__ __launch_bounds__(256) void transpose_planes_k(
    const float* __restrict__ in, float* __restrict__ out)
{
  __shared__ float sm[NC][64 + 1];
  int b   = blockIdx.x;            // = p*4096 + y*8 + xb
  int xb  = b & 7;
  int y   = (b >> 3) & 511;
  int p   = b >> 12;
  int x0  = xb << 6;
  int tid = threadIdx.x;
#pragma unroll
  for (int k = 0; k < 4; ++k) {
    int e = tid + k * 256;
    int c = e >> 6, x = e & 63;
    sm[c][x] = in[(size_t)((p * NC + c) * RES + y) * RES + x0 + x];
  }
  __syncthreads();
#pragma unroll
  for (int k = 0; k < 4; ++k) {
    int e = tid + k * 256;
    int x = e >> 4, c = e & 15;
    out[(size_t)((p * RES + y) * RES + x0 + x) * NC + c] = sm[c][x];
  }
}

// Transpose lines [3][16][512] -> [3][512][16]
__global__ void transpose_lines_k(const float* __restrict__ in, float* __restrict__ out)
{
  int i = blockIdx.x * 256 + threadIdx.x;
  if (i >= NPLANES * RES * NC) return;
  int c = i & 15;
  int l = (i >> 4) & 511;
  int p = i >> 13;
  out[i] = in[(p * NC + c) * RES + l];
}

// ---------------------------------------------------------------------------
// Main fused kernel: sample -> coef -> pfeat -> 19x32 matmul -> direct stores.
// No output-staging LDS: each lane stores its 32 floats as 8x float4
// (128 contiguous bytes/lane -> every HBM line fully written). LDS ~2.6 KB
// so occupancy is VGPR-limited (~6 waves/SIMD at <=85 VGPR).
// ---------------------------------------------------------------------------
template <bool TP>
__global__ __launch_bounds__(256, 6) void visnerf_main_k(
    const float* __restrict__ pts, const float* __restrict__ ts,
    const float* __restrict__ planes, const float* __restrict__ lines,
    const float* __restrict__ pg, const float* __restrict__ W,
    float* __restrict__ out, int N)
{
  __shared__ __align__(16) float sW[32 * 20];   // W padded [32][20], pad = 0
  __shared__ float spg[9];
  int tid = threadIdx.x;
  for (int e = tid; e < 640; e += 256) {
    int o = e / 20, c = e - o * 20;
    sW[e] = (c < 19) ? W[o * 19 + c] : 0.0f;
  }
  if (tid < 9) spg[tid] = pg[tid];
  __syncthreads();

  int i = blockIdx.x * 256 + tid;
  if (i >= N) return;  // no barriers after this point

  float px = pts[i * 3 + 0], py = pts[i * 3 + 1], pz = pts[i * 3 + 2];
  float t  = ts[i];

  const float kk = (float)(2.0 / (-2.0 * 1.3));  // normalize_aabb slope
  float nn[3];
  nn[0] = (px - 1.3f) * kk - 1.0f;
  nn[1] = (py - 1.3f) * kk - 1.0f;
  nn[2] = (pz - 1.3f) * kk - 1.0f;

  float feats[20];
#pragma unroll
  for (int c = 0; c < 20; ++c) feats[c] = 0.0f;

  const int matx[3] = {0, 0, 1};
  const int maty[3] = {1, 2, 2};
  const int vecm[3] = {2, 1, 0};

#pragma unroll
  for (int q = 0; q < 3; ++q) {
    float x  = nn[matx[q]], y = nn[maty[q]], lc = nn[vecm[q]];
    float ix = (x + 1.0f) * 0.5f * (float)(RES - 1);
    float iy = (y + 1.0f) * 0.5f * (float)(RES - 1);
    float fx = floorf(ix), fy = floorf(iy);
    float wx = ix - fx, wy = iy - fy;
    int x0 = (int)fx; x0 = x0 < 0 ? 0 : (x0 > RES - 1 ? RES - 1 : x0);
    int y0 = (int)fy; y0 = y0 < 0 ? 0 : (y0 > RES - 1 ? RES - 1 : y0);
    int x1 = (x0 + 1 > RES - 1) ? RES - 1 : x0 + 1;
    int y1 = (y0 + 1 > RES - 1) ? RES - 1 : y0 + 1;

    float il = (lc + 1.0f) * 0.5f * (float)(RES - 1);
    float fl = floorf(il);
    float wl = il - fl;
    int l0 = (int)fl; l0 = l0 < 0 ? 0 : (l0 > RES - 1 ? RES - 1 : l0);
    int l1 = (l0 + 1 > RES - 1) ? RES - 1 : l0 + 1;

    float w00 = (1.0f - wy) * (1.0f - wx);
    float w01 = (1.0f - wy) * wx;
    float w10 = wy * (1.0f - wx);
    float w11 = wy * wx;
    float wl0 = 1.0f - wl;

    if (TP) {
      const float4* t00 = (const float4*)(planes + (size_t)((q * RES + y0) * RES + x0) * NC);
      const float4* t01 = (const float4*)(planes + (size_t)((q * RES + y0) * RES + x1) * NC);
      const float4* t10 = (const float4*)(planes + (size_t)((q * RES + y1) * RES + x0) * NC);
      const float4* t11 = (const float4*)(planes + (size_t)((q * RES + y1) * RES + x1) * NC);
      const float4* L0  = (const float4*)(lines + (size_t)(q * RES + l0) * NC);
      const float4* L1  = (const float4*)(lines + (size_t)(q * RES + l1) * NC);
#pragma unroll
      for (int k = 0; k < 4; ++k) {
        float4 a = t00[k], b = t01[k], c4 = t10[k], d = t11[k];
        float4 e0 = L0[k], e1 = L1[k];
        feats[4 * k + 0] += (w00 * a.x + w01 * b.x + w10 * c4.x + w11 * d.x) * (wl0 * e0.x + wl * e1.x);
        feats[4 * k + 1] += (w00 * a.y + w01 * b.y + w10 * c4.y + w11 * d.y) * (wl0 * e0.y + wl * e1.y);
        feats[4 * k + 2] += (w00 * a.z + w01 * b.z + w10 * c4.z + w11 * d.z) * (wl0 * e0.z + wl * e1.z);
        feats[4 * k + 3] += (w00 * a.w + w01 * b.w + w10 * c4.w + w11 * d.w) * (wl0 * e0.w + wl * e1.w);
      }
    } else {
#pragma unroll 4
      for (int c = 0; c < NC; ++c) {
        const float* pl = planes + (size_t)(q * NC + c) * RES * RES;
        float a  = pl[y0 * RES + x0], b = pl[y0 * RES + x1];
        float c2 = pl[y1 * RES + x0], d = pl[y1 * RES + x1];
        const float* ln = lines + (size_t)(q * NC + c) * RES;
        float lf = ln[l0] * wl0 + ln[l1] * wl;
        feats[c] += (w00 * a + w01 * b + w10 * c2 + w11 * d) * lf;
      }
    }
  }

  // pfeat: _sample1d(params_grid [3,3], t)
  {
    float it = (t + 1.0f) * 0.5f * 2.0f;
    float ft = floorf(it);
    float wt = it - ft;
    int t0 = (int)ft; t0 = t0 < 0 ? 0 : (t0 > 2 ? 2 : t0);
    int t1 = (t0 + 1 > 2) ? 2 : t0 + 1;
    feats[16] = spg[0 + t0] * (1.0f - wt) + spg[0 + t1] * wt;
    feats[17] = spg[3 + t0] * (1.0f - wt) + spg[3 + t1] * wt;
    feats[18] = spg[6 + t0] * (1.0f - wt) + spg[6 + t1] * wt;
    feats[19] = 0.0f;
  }

  // 19->32 matmul (pad to 20, float4 broadcast reads from LDS)
  float res[32];
#pragma unroll
  for (int o = 0; o < 32; ++o) {
    const float4* wr = (const float4*)(sW + o * 20);
    float acc = 0.0f;
#pragma unroll
    for (int k = 0; k < 5; ++k) {
      float4 wv = wr[k];
      acc += feats[4 * k + 0] * wv.x + feats[4 * k + 1] * wv.y +
             feats[4 * k + 2] * wv.z + feats[4 * k + 3] * wv.w;
    }
    res[o] = acc;
  }

  // direct stores: 8x float4, 128 contiguous bytes per lane
  float4* op = (float4*)(out + (size_t)i * 32);
#pragma unroll
  for (int k = 0; k < 8; ++k) {
    float4 v;
    v.x = res[4 * k + 0];
    v.y = res[4 * k + 1];
    v.z = res[4 * k + 2];
    v.w = res[4 * k + 3];
    op[k] = v;
  }
}

extern "C" void kernel_launch(void* const* d_in, const int* in_sizes, int n_in,
                              void* d_out, int out_size, void* d_ws, size_t ws_size,
                              hipStream_t stream)
{
  const float* pts    = (const float*)d_in[0];
  const float* ts     = (const float*)d_in[1];
  const float* planes = (const float*)d_in[2];
  const float* lines  = (const float*)d_in[3];
  const float* pg     = (const float*)d_in[4];
  const float* W      = (const float*)d_in[5];
  float* out = (float*)d_out;
  int N = in_sizes[0] / 3;

  size_t planesT_bytes = (size_t)NPLANES * RES * RES * NC * sizeof(float);
  size_t linesT_bytes  = (size_t)NPLANES * RES * NC * sizeof(float);
  int blocksMain = (N + 255) / 256;

  if (ws_size >= planesT_bytes + linesT_bytes) {
    float* planesT = (float*)d_ws;
    float* linesT  = (float*)((char*)d_ws + planesT_bytes);
    transpose_planes_k<<<NPLANES * RES * (RES / 64), 256, 0, stream>>>(planes, planesT);
    transpose_lines_k<<<(NPLANES * RES * NC + 255) / 256, 256, 0, stream>>>(lines, linesT);
    visnerf_main_k<true><<<blocksMain, 256, 0, stream>>>(pts, ts, planesT, linesT, pg, W, out, N);
  } else {
    visnerf_main_k<false><<<blocksMain, 256, 0, stream>>>(pts, ts, planes, lines, pg, W, out, N);
  }
}

// Round 3
// 1017.685 us; speedup vs baseline: 1.4120x; 1.4120x over previous
//
#include <hip/hip_runtime.h>

#define RES 512
#define NC 16
#define NPLANES 3

// ---------------------------------------------------------------------------
// Transpose planes [3][16][512][512] -> [3][512][512][16] (channel innermost)
// so a bilinear texel fetch of 16 channels is one contiguous 64B line.
// ---------------------------------------------------------------------------
__global__ __launch_bounds__(256) void transpose_planes_k(
    const float* __restrict__ in, float* __restrict__ out)
{
  __shared__ float sm[NC][64 + 1];
  int b   = blockIdx.x;            // = p*4096 + y*8 + xb
  int xb  = b & 7;
  int y   = (b >> 3) & 511;
  int p   = b >> 12;
  int x0  = xb << 6;
  int tid = threadIdx.x;
#pragma unroll
  for (int k = 0; k < 4; ++k) {
    int e = tid + k * 256;
    int c = e >> 6, x = e & 63;
    sm[c][x] = in[(size_t)((p * NC + c) * RES + y) * RES + x0 + x];
  }
  __syncthreads();
#pragma unroll
  for (int k = 0; k < 4; ++k) {
    int e = tid + k * 256;
    int x = e >> 4, c = e & 15;
    out[(size_t)((p * RES + y) * RES + x0 + x) * NC + c] = sm[c][x];
  }
}

// Transpose lines [3][16][512] -> [3][512][16]
__global__ void transpose_lines_k(const float* __restrict__ in, float* __restrict__ out)
{
  int i = blockIdx.x * 256 + threadIdx.x;
  if (i >= NPLANES * RES * NC) return;
  int c = i & 15;
  int l = (i >> 4) & 511;
  int p = i >> 13;
  out[i] = in[(p * NC + c) * RES + l];
}

// ---------------------------------------------------------------------------
// Main fused kernel: sample -> coef -> pfeat -> 19x32 matmul fused with
// direct float4 stores (4 outputs at a time -> no res[32] array, low VGPR).
// No launch_bounds min-wave clamp: R2 showed forcing 6 waves/EU spills
// (VGPR 40, 4.3GB scratch traffic). Let allocator pick ~64-80 VGPR.
// ---------------------------------------------------------------------------
template <bool TP>
__global__ __launch_bounds__(256) void visnerf_main_k(
    const float* __restrict__ pts, const float* __restrict__ ts,
    const float* __restrict__ planes, const float* __restrict__ lines,
    const float* __restrict__ pg, const float* __restrict__ W,
    float* __restrict__ out, int N)
{
  __shared__ __align__(16) float sW[32 * 20];   // W padded [32][20], pad = 0
  __shared__ float spg[9];
  int tid = threadIdx.x;
  for (int e = tid; e < 640; e += 256) {
    int o = e / 20, c = e - o * 20;
    sW[e] = (c < 19) ? W[o * 19 + c] : 0.0f;
  }
  if (tid < 9) spg[tid] = pg[tid];
  __syncthreads();

  int i = blockIdx.x * 256 + tid;
  if (i >= N) return;  // no barriers after this point

  float px = pts[i * 3 + 0], py = pts[i * 3 + 1], pz = pts[i * 3 + 2];
  float t  = ts[i];

  const float kk = (float)(2.0 / (-2.0 * 1.3));  // normalize_aabb slope
  float nn[3];
  nn[0] = (px - 1.3f) * kk - 1.0f;
  nn[1] = (py - 1.3f) * kk - 1.0f;
  nn[2] = (pz - 1.3f) * kk - 1.0f;

  float feats[20];
#pragma unroll
  for (int c = 0; c < 20; ++c) feats[c] = 0.0f;

  const int matx[3] = {0, 0, 1};
  const int maty[3] = {1, 2, 2};
  const int vecm[3] = {2, 1, 0};

#pragma unroll
  for (int q = 0; q < 3; ++q) {
    float x  = nn[matx[q]], y = nn[maty[q]], lc = nn[vecm[q]];
    float ix = (x + 1.0f) * 0.5f * (float)(RES - 1);
    float iy = (y + 1.0f) * 0.5f * (float)(RES - 1);
    float fx = floorf(ix), fy = floorf(iy);
    float wx = ix - fx, wy = iy - fy;
    int x0 = (int)fx; x0 = x0 < 0 ? 0 : (x0 > RES - 1 ? RES - 1 : x0);
    int y0 = (int)fy; y0 = y0 < 0 ? 0 : (y0 > RES - 1 ? RES - 1 : y0);
    int x1 = (x0 + 1 > RES - 1) ? RES - 1 : x0 + 1;
    int y1 = (y0 + 1 > RES - 1) ? RES - 1 : y0 + 1;

    float il = (lc + 1.0f) * 0.5f * (float)(RES - 1);
    float fl = floorf(il);
    float wl = il - fl;
    int l0 = (int)fl; l0 = l0 < 0 ? 0 : (l0 > RES - 1 ? RES - 1 : l0);
    int l1 = (l0 + 1 > RES - 1) ? RES - 1 : l0 + 1;

    float w00 = (1.0f - wy) * (1.0f - wx);
    float w01 = (1.0f - wy) * wx;
    float w10 = wy * (1.0f - wx);
    float w11 = wy * wx;
    float wl0 = 1.0f - wl;

    if (TP) {
      const float4* t00 = (const float4*)(planes + (size_t)((q * RES + y0) * RES + x0) * NC);
      const float4* t01 = (const float4*)(planes + (size_t)((q * RES + y0) * RES + x1) * NC);
      const float4* t10 = (const float4*)(planes + (size_t)((q * RES + y1) * RES + x0) * NC);
      const float4* t11 = (const float4*)(planes + (size_t)((q * RES + y1) * RES + x1) * NC);
      const float4* L0  = (const float4*)(lines + (size_t)(q * RES + l0) * NC);
      const float4* L1  = (const float4*)(lines + (size_t)(q * RES + l1) * NC);
#pragma unroll
      for (int k = 0; k < 4; ++k) {
        float4 a = t00[k], b = t01[k], c4 = t10[k], d = t11[k];
        float4 e0 = L0[k], e1 = L1[k];
        feats[4 * k + 0] += (w00 * a.x + w01 * b.x + w10 * c4.x + w11 * d.x) * (wl0 * e0.x + wl * e1.x);
        feats[4 * k + 1] += (w00 * a.y + w01 * b.y + w10 * c4.y + w11 * d.y) * (wl0 * e0.y + wl * e1.y);
        feats[4 * k + 2] += (w00 * a.z + w01 * b.z + w10 * c4.z + w11 * d.z) * (wl0 * e0.z + wl * e1.z);
        feats[4 * k + 3] += (w00 * a.w + w01 * b.w + w10 * c4.w + w11 * d.w) * (wl0 * e0.w + wl * e1.w);
      }
    } else {
#pragma unroll 4
      for (int c = 0; c < NC; ++c) {
        const float* pl = planes + (size_t)(q * NC + c) * RES * RES;
        float a  = pl[y0 * RES + x0], b = pl[y0 * RES + x1];
        float c2 = pl[y1 * RES + x0], d = pl[y1 * RES + x1];
        const float* ln = lines + (size_t)(q * NC + c) * RES;
        float lf = ln[l0] * wl0 + ln[l1] * wl;
        feats[c] += (w00 * a + w01 * b + w10 * c2 + w11 * d) * lf;
      }
    }
  }

  // pfeat: _sample1d(params_grid [3,3], t)
  {
    float it = (t + 1.0f) * 0.5f * 2.0f;
    float ft = floorf(it);
    float wt = it - ft;
    int t0 = (int)ft; t0 = t0 < 0 ? 0 : (t0 > 2 ? 2 : t0);
    int t1 = (t0 + 1 > 2) ? 2 : t0 + 1;
    feats[16] = spg[0 + t0] * (1.0f - wt) + spg[0 + t1] * wt;
    feats[17] = spg[3 + t0] * (1.0f - wt) + spg[3 + t1] * wt;
    feats[18] = spg[6 + t0] * (1.0f - wt) + spg[6 + t1] * wt;
    feats[19] = 0.0f;
  }

  // 19->32 matmul fused with stores: 4 outputs -> one float4 store, x8.
  // Only 4 result registers live at a time.
  float4* op = (float4*)(out + (size_t)i * 32);
#pragma unroll
  for (int g = 0; g < 8; ++g) {
    float4 v;
    float* vp = &v.x;
#pragma unroll
    for (int j = 0; j < 4; ++j) {
      int o = g * 4 + j;
      const float4* wr = (const float4*)(sW + o * 20);
      float acc = 0.0f;
#pragma unroll
      for (int k = 0; k < 5; ++k) {
        float4 wv = wr[k];
        acc += feats[4 * k + 0] * wv.x + feats[4 * k + 1] * wv.y +
               feats[4 * k + 2] * wv.z + feats[4 * k + 3] * wv.w;
      }
      vp[j] = acc;
    }
    op[g] = v;
  }
}

extern "C" void kernel_launch(void* const* d_in, const int* in_sizes, int n_in,
                              void* d_out, int out_size, void* d_ws, size_t ws_size,
                              hipStream_t stream)
{
  const float* pts    = (const float*)d_in[0];
  const float* ts     = (const float*)d_in[1];
  const float* planes = (const float*)d_in[2];
  const float* lines  = (const float*)d_in[3];
  const float* pg     = (const float*)d_in[4];
  const float* W      = (const float*)d_in[5];
  float* out = (float*)d_out;
  int N = in_sizes[0] / 3;

  size_t planesT_bytes = (size_t)NPLANES * RES * RES * NC * sizeof(float);
  size_t linesT_bytes  = (size_t)NPLANES * RES * NC * sizeof(float);
  int blocksMain = (N + 255) / 256;

  if (ws_size >= planesT_bytes + linesT_bytes) {
    float* planesT = (float*)d_ws;
    float* linesT  = (float*)((char*)d_ws + planesT_bytes);
    transpose_planes_k<<<NPLANES * RES * (RES / 64), 256, 0, stream>>>(planes, planesT);
    transpose_lines_k<<<(NPLANES * RES * NC + 255) / 256, 256, 0, stream>>>(lines, linesT);
    visnerf_main_k<true><<<blocksMain, 256, 0, stream>>>(pts, ts, planesT, linesT, pg, W, out, N);
  } else {
    visnerf_main_k<false><<<blocksMain, 256, 0, stream>>>(pts, ts, planes, lines, pg, W, out, N);
  }
}

// Round 5
// 476.193 us; speedup vs baseline: 3.0176x; 2.1371x over previous
//
#include <hip/hip_runtime.h>

#define RES 512
#define NC 16
#define NPLANES 3

typedef float f32x4 __attribute__((ext_vector_type(4)));

static __device__ inline float nt_loadf(const float* p) { return __builtin_nontemporal_load(p); }
static __device__ inline void nt_store4(float* p, f32x4 v) {
  __builtin_nontemporal_store(v, (f32x4*)p);
}

// ---------------------------------------------------------------------------
// Transpose planes [3][16][512][512] -> [3][512][512][16] (channel innermost)
// so a bilinear texel fetch of 16 channels is one contiguous 64B line.
// Input is read once -> nontemporal loads. Output planesT must stay cached
// (read 24x by main kernel) -> normal stores.
// ---------------------------------------------------------------------------
__global__ __launch_bounds__(256) void transpose_planes_k(
    const float* __restrict__ in, float* __restrict__ out)
{
  __shared__ float sm[NC][64 + 1];
  int b   = blockIdx.x;            // = p*4096 + y*8 + xb
  int xb  = b & 7;
  int y   = (b >> 3) & 511;
  int p   = b >> 12;
  int x0  = xb << 6;
  int tid = threadIdx.x;
#pragma unroll
  for (int k = 0; k < 4; ++k) {
    int e = tid + k * 256;
    int c = e >> 6, x = e & 63;
    sm[c][x] = nt_loadf(&in[(size_t)((p * NC + c) * RES + y) * RES + x0 + x]);
  }
  __syncthreads();
#pragma unroll
  for (int k = 0; k < 4; ++k) {
    int e = tid + k * 256;
    int x = e >> 4, c = e & 15;
    out[(size_t)((p * RES + y) * RES + x0 + x) * NC + c] = sm[c][x];
  }
}

// Transpose lines [3][16][512] -> [3][512][16]
__global__ void transpose_lines_k(const float* __restrict__ in, float* __restrict__ out)
{
  int i = blockIdx.x * 256 + threadIdx.x;
  if (i >= NPLANES * RES * NC) return;
  int c = i & 15;
  int l = (i >> 4) & 511;
  int p = i >> 13;
  out[i] = nt_loadf(&in[(p * NC + c) * RES + l]);
}

// ---------------------------------------------------------------------------
// Main fused kernel (R1 structure): sample -> coef -> pfeat -> 19x32 matmul
// -> LDS-staged swizzled coalesced stores (full-line per instruction).
// NEW vs R1: output stores + pts/ts loads are NON-TEMPORAL so the 268MB
// write stream does not evict the 50MB planesT working set from L2/L3.
// ---------------------------------------------------------------------------
template <bool TP>
__global__ __launch_bounds__(256) void visnerf_main_k(
    const float* __restrict__ pts, const float* __restrict__ ts,
    const float* __restrict__ planes, const float* __restrict__ lines,
    const float* __restrict__ pg, const float* __restrict__ W,
    float* __restrict__ out, int N)
{
  __shared__ __align__(16) float sW[32 * 20];   // W padded [32][20], pad = 0
  __shared__ __align__(16) float st[256 * 32];  // output staging (swizzled)
  __shared__ float spg[9];
  int tid = threadIdx.x;
  for (int e = tid; e < 640; e += 256) {
    int o = e / 20, c = e - o * 20;
    sW[e] = (c < 19) ? W[o * 19 + c] : 0.0f;
  }
  if (tid < 9) spg[tid] = pg[tid];
  __syncthreads();

  int i  = blockIdx.x * 256 + tid;
  int ii = (i < N) ? i : (N - 1);
  float px = nt_loadf(&pts[ii * 3 + 0]);
  float py = nt_loadf(&pts[ii * 3 + 1]);
  float pz = nt_loadf(&pts[ii * 3 + 2]);
  float t  = nt_loadf(&ts[ii]);

  const float kk = (float)(2.0 / (-2.0 * 1.3));  // normalize_aabb slope
  float nn[3];
  nn[0] = (px - 1.3f) * kk - 1.0f;
  nn[1] = (py - 1.3f) * kk - 1.0f;
  nn[2] = (pz - 1.3f) * kk - 1.0f;

  float feats[20];
#pragma unroll
  for (int c = 0; c < 20; ++c) feats[c] = 0.0f;

  const int matx[3] = {0, 0, 1};
  const int maty[3] = {1, 2, 2};
  const int vecm[3] = {2, 1, 0};

#pragma unroll
  for (int q = 0; q < 3; ++q) {
    float x  = nn[matx[q]], y = nn[maty[q]], lc = nn[vecm[q]];
    float ix = (x + 1.0f) * 0.5f * (float)(RES - 1);
    float iy = (y + 1.0f) * 0.5f * (float)(RES - 1);
    float fx = floorf(ix), fy = floorf(iy);
    float wx = ix - fx, wy = iy - fy;
    int x0 = (int)fx; x0 = x0 < 0 ? 0 : (x0 > RES - 1 ? RES - 1 : x0);
    int y0 = (int)fy; y0 = y0 < 0 ? 0 : (y0 > RES - 1 ? RES - 1 : y0);
    int x1 = (x0 + 1 > RES - 1) ? RES - 1 : x0 + 1;
    int y1 = (y0 + 1 > RES - 1) ? RES - 1 : y0 + 1;

    float il = (lc + 1.0f) * 0.5f * (float)(RES - 1);
    float fl = floorf(il);
    float wl = il - fl;
    int l0 = (int)fl; l0 = l0 < 0 ? 0 : (l0 > RES - 1 ? RES - 1 : l0);
    int l1 = (l0 + 1 > RES - 1) ? RES - 1 : l0 + 1;

    float w00 = (1.0f - wy) * (1.0f - wx);
    float w01 = (1.0f - wy) * wx;
    float w10 = wy * (1.0f - wx);
    float w11 = wy * wx;
    float wl0 = 1.0f - wl;

    if (TP) {
      const float4* t00 = (const float4*)(planes + (size_t)((q * RES + y0) * RES + x0) * NC);
      const float4* t01 = (const float4*)(planes + (size_t)((q * RES + y0) * RES + x1) * NC);
      const float4* t10 = (const float4*)(planes + (size_t)((q * RES + y1) * RES + x0) * NC);
      const float4* t11 = (const float4*)(planes + (size_t)((q * RES + y1) * RES + x1) * NC);
      const float4* L0  = (const float4*)(lines + (size_t)(q * RES + l0) * NC);
      const float4* L1  = (const float4*)(lines + (size_t)(q * RES + l1) * NC);
#pragma unroll
      for (int k = 0; k < 4; ++k) {
        float4 a = t00[k], b = t01[k], c4 = t10[k], d = t11[k];
        float4 e0 = L0[k], e1 = L1[k];
        feats[4 * k + 0] += (w00 * a.x + w01 * b.x + w10 * c4.x + w11 * d.x) * (wl0 * e0.x + wl * e1.x);
        feats[4 * k + 1] += (w00 * a.y + w01 * b.y + w10 * c4.y + w11 * d.y) * (wl0 * e0.y + wl * e1.y);
        feats[4 * k + 2] += (w00 * a.z + w01 * b.z + w10 * c4.z + w11 * d.z) * (wl0 * e0.z + wl * e1.z);
        feats[4 * k + 3] += (w00 * a.w + w01 * b.w + w10 * c4.w + w11 * d.w) * (wl0 * e0.w + wl * e1.w);
      }
    } else {
#pragma unroll 4
      for (int c = 0; c < NC; ++c) {
        const float* pl = planes + (size_t)(q * NC + c) * RES * RES;
        float a  = pl[y0 * RES + x0], b = pl[y0 * RES + x1];
        float c2 = pl[y1 * RES + x0], d = pl[y1 * RES + x1];
        const float* ln = lines + (size_t)(q * NC + c) * RES;
        float lf = ln[l0] * wl0 + ln[l1] * wl;
        feats[c] += (w00 * a + w01 * b + w10 * c2 + w11 * d) * lf;
      }
    }
  }

  // pfeat: _sample1d(params_grid [3,3], t)
  {
    float it = (t + 1.0f) * 0.5f * 2.0f;
    float ft = floorf(it);
    float wt = it - ft;
    int t0 = (int)ft; t0 = t0 < 0 ? 0 : (t0 > 2 ? 2 : t0);
    int t1 = (t0 + 1 > 2) ? 2 : t0 + 1;
    feats[16] = spg[0 + t0] * (1.0f - wt) + spg[0 + t1] * wt;
    feats[17] = spg[3 + t0] * (1.0f - wt) + spg[3 + t1] * wt;
    feats[18] = spg[6 + t0] * (1.0f - wt) + spg[6 + t1] * wt;
    feats[19] = 0.0f;
  }

  // 19->32 matmul (pad to 20, float4 broadcast reads from LDS)
  float res[32];
#pragma unroll
  for (int o = 0; o < 32; ++o) {
    const float4* wr = (const float4*)(sW + o * 20);
    float acc = 0.0f;
#pragma unroll
    for (int k = 0; k < 5; ++k) {
      float4 wv = wr[k];
      acc += feats[4 * k + 0] * wv.x + feats[4 * k + 1] * wv.y +
             feats[4 * k + 2] * wv.z + feats[4 * k + 3] * wv.w;
    }
    res[o] = acc;
  }

  // stage to LDS with rotate-swizzle so both phases are conflict-free,
  // then write fully-coalesced float4s (full 128B lines per instruction),
  // NON-TEMPORAL so the write stream doesn't evict planesT from L2/L3.
#pragma unroll
  for (int o = 0; o < 32; ++o)
    st[tid * 32 + ((o + tid) & 31)] = res[o];
  __syncthreads();

  size_t gbase = (size_t)blockIdx.x * 8192;
  size_t total = (size_t)N * 32;
#pragma unroll
  for (int k = 0; k < 8; ++k) {
    int idx = tid + k * 256;
    int j   = idx * 4;
    int pq  = j >> 5;
    f32x4 v;
    v.x = st[pq * 32 + (((j & 31) + 0 + pq) & 31)];
    v.y = st[pq * 32 + (((j & 31) + 1 + pq) & 31)];
    v.z = st[pq * 32 + (((j & 31) + 2 + pq) & 31)];
    v.w = st[pq * 32 + (((j & 31) + 3 + pq) & 31)];
    if (gbase + j + 4 <= total) {
      nt_store4(out + gbase + j, v);
    }
  }
}

extern "C" void kernel_launch(void* const* d_in, const int* in_sizes, int n_in,
                              void* d_out, int out_size, void* d_ws, size_t ws_size,
                              hipStream_t stream)
{
  const float* pts    = (const float*)d_in[0];
  const float* ts     = (const float*)d_in[1];
  const float* planes = (const float*)d_in[2];
  const float* lines  = (const float*)d_in[3];
  const float* pg     = (const float*)d_in[4];
  const float* W      = (const float*)d_in[5];
  float* out = (float*)d_out;
  int N = in_sizes[0] / 3;

  size_t planesT_bytes = (size_t)NPLANES * RES * RES * NC * sizeof(float);
  size_t linesT_bytes  = (size_t)NPLANES * RES * NC * sizeof(float);
  int blocksMain = (N + 255) / 256;

  if (ws_size >= planesT_bytes + linesT_bytes) {
    float* planesT = (float*)d_ws;
    float* linesT  = (float*)((char*)d_ws + planesT_bytes);
    transpose_planes_k<<<NPLANES * RES * (RES / 64), 256, 0, stream>>>(planes, planesT);
    transpose_lines_k<<<(NPLANES * RES * NC + 255) / 256, 256, 0, stream>>>(lines, linesT);
    visnerf_main_k<true><<<blocksMain, 256, 0, stream>>>(pts, ts, planesT, linesT, pg, W, out, N);
  } else {
    visnerf_main_k<false><<<blocksMain, 256, 0, stream>>>(pts, ts, planes, lines, pg, W, out, N);
  }
}

// Round 6
// 321.487 us; speedup vs baseline: 4.4697x; 1.4812x over previous
//
#include <hip/hip_runtime.h>
#include <hip/hip_bf16.h>

#define RES 512
#define NC 16
#define NPLANES 3

typedef float f32x4 __attribute__((ext_vector_type(4)));

static __device__ inline float nt_loadf(const float* p) { return __builtin_nontemporal_load(p); }
static __device__ inline void nt_store4(float* p, f32x4 v) {
  __builtin_nontemporal_store(v, (f32x4*)p);
}
static __device__ inline float bf_lo(unsigned u) { return __uint_as_float(u << 16); }
static __device__ inline float bf_hi(unsigned u) { return __uint_as_float(u & 0xFFFF0000u); }

// ---------------------------------------------------------------------------
// Transpose planes [3][16][512][512] f32 -> [3][512][512][16] bf16
// (channel innermost): one bilinear texel = 16 bf16 = 32B = 2 uint4 loads.
// Working set 25MB -> stays L3-resident under the 268MB output write stream.
// ---------------------------------------------------------------------------
__global__ __launch_bounds__(256) void transpose_planes_k(
    const float* __restrict__ in, __hip_bfloat16* __restrict__ out)
{
  __shared__ float sm[NC][64 + 1];
  int b   = blockIdx.x;            // = p*4096 + y*8 + xb
  int xb  = b & 7;
  int y   = (b >> 3) & 511;
  int p   = b >> 12;
  int x0  = xb << 6;
  int tid = threadIdx.x;
#pragma unroll
  for (int k = 0; k < 4; ++k) {
    int e = tid + k * 256;
    int c = e >> 6, x = e & 63;
    sm[c][x] = nt_loadf(&in[(size_t)((p * NC + c) * RES + y) * RES + x0 + x]);
  }
  __syncthreads();
#pragma unroll
  for (int k = 0; k < 4; ++k) {
    int e = tid + k * 256;
    int x = e >> 4, c = e & 15;
    out[(size_t)((p * RES + y) * RES + x0 + x) * NC + c] = __float2bfloat16(sm[c][x]);
  }
}

// Transpose lines [3][16][512] -> [3][512][16], keep f32 (96KB, L2-resident)
__global__ void transpose_lines_k(const float* __restrict__ in, float* __restrict__ out)
{
  int i = blockIdx.x * 256 + threadIdx.x;
  if (i >= NPLANES * RES * NC) return;
  int c = i & 15;
  int l = (i >> 4) & 511;
  int p = i >> 13;
  out[i] = nt_loadf(&in[(p * NC + c) * RES + l]);
}

// ---------------------------------------------------------------------------
// Main fused kernel: bf16 plane gather -> coef -> pfeat -> 19x32 matmul ->
// LDS-staged swizzled coalesced nt stores (full 128B lines per instruction).
// ---------------------------------------------------------------------------
template <bool TP>
__global__ __launch_bounds__(256) void visnerf_main_k(
    const float* __restrict__ pts, const float* __restrict__ ts,
    const __hip_bfloat16* __restrict__ planesb, const float* __restrict__ lines,
    const float* __restrict__ planes_f32, const float* __restrict__ lines_f32,
    const float* __restrict__ pg, const float* __restrict__ W,
    float* __restrict__ out, int N)
{
  __shared__ __align__(16) float sW[32 * 20];   // W padded [32][20], pad = 0
  __shared__ __align__(16) float st[256 * 32];  // output staging (swizzled)
  __shared__ float spg[9];
  int tid = threadIdx.x;
  for (int e = tid; e < 640; e += 256) {
    int o = e / 20, c = e - o * 20;
    sW[e] = (c < 19) ? W[o * 19 + c] : 0.0f;
  }
  if (tid < 9) spg[tid] = pg[tid];
  __syncthreads();

  int i  = blockIdx.x * 256 + tid;
  int ii = (i < N) ? i : (N - 1);
  float px = nt_loadf(&pts[ii * 3 + 0]);
  float py = nt_loadf(&pts[ii * 3 + 1]);
  float pz = nt_loadf(&pts[ii * 3 + 2]);
  float t  = nt_loadf(&ts[ii]);

  const float kk = (float)(2.0 / (-2.0 * 1.3));  // normalize_aabb slope
  float nn[3];
  nn[0] = (px - 1.3f) * kk - 1.0f;
  nn[1] = (py - 1.3f) * kk - 1.0f;
  nn[2] = (pz - 1.3f) * kk - 1.0f;

  float feats[20];
#pragma unroll
  for (int c = 0; c < 20; ++c) feats[c] = 0.0f;

  const int matx[3] = {0, 0, 1};
  const int maty[3] = {1, 2, 2};
  const int vecm[3] = {2, 1, 0};

#pragma unroll
  for (int q = 0; q < 3; ++q) {
    float x  = nn[matx[q]], y = nn[maty[q]], lc = nn[vecm[q]];
    float ix = (x + 1.0f) * 0.5f * (float)(RES - 1);
    float iy = (y + 1.0f) * 0.5f * (float)(RES - 1);
    float fx = floorf(ix), fy = floorf(iy);
    float wx = ix - fx, wy = iy - fy;
    int x0 = (int)fx; x0 = x0 < 0 ? 0 : (x0 > RES - 1 ? RES - 1 : x0);
    int y0 = (int)fy; y0 = y0 < 0 ? 0 : (y0 > RES - 1 ? RES - 1 : y0);
    int x1 = (x0 + 1 > RES - 1) ? RES - 1 : x0 + 1;
    int y1 = (y0 + 1 > RES - 1) ? RES - 1 : y0 + 1;

    float il = (lc + 1.0f) * 0.5f * (float)(RES - 1);
    float fl = floorf(il);
    float wl = il - fl;
    int l0 = (int)fl; l0 = l0 < 0 ? 0 : (l0 > RES - 1 ? RES - 1 : l0);
    int l1 = (l0 + 1 > RES - 1) ? RES - 1 : l0 + 1;

    float w00 = (1.0f - wy) * (1.0f - wx);
    float w01 = (1.0f - wy) * wx;
    float w10 = wy * (1.0f - wx);
    float w11 = wy * wx;
    float wl0 = 1.0f - wl;

    if (TP) {
      const uint4* ta = (const uint4*)(planesb + (size_t)((q * RES + y0) * RES + x0) * NC);
      const uint4* tb = (const uint4*)(planesb + (size_t)((q * RES + y0) * RES + x1) * NC);
      const uint4* tc = (const uint4*)(planesb + (size_t)((q * RES + y1) * RES + x0) * NC);
      const uint4* td = (const uint4*)(planesb + (size_t)((q * RES + y1) * RES + x1) * NC);
      const float4* L0 = (const float4*)(lines + (size_t)(q * RES + l0) * NC);
      const float4* L1 = (const float4*)(lines + (size_t)(q * RES + l1) * NC);
#pragma unroll
      for (int h = 0; h < 2; ++h) {   // 8 channels per half
        uint4 ua = ta[h], ub = tb[h], uc = tc[h], ud = td[h];
        float4 e0a = L0[2 * h + 0], e0b = L0[2 * h + 1];
        float4 e1a = L1[2 * h + 0], e1b = L1[2 * h + 1];
        const unsigned* pa = &ua.x;
        const unsigned* pb = &ub.x;
        const unsigned* pc = &uc.x;
        const unsigned* pd = &ud.x;
        const float* q0 = &e0a.x;  // 8 consecutive floats e0a..e0b
        const float* q1 = &e1a.x;
#pragma unroll
        for (int w = 0; w < 4; ++w) {  // each uint = 2 channels
          int c0 = h * 8 + 2 * w;
          float pf0 = w00 * bf_lo(pa[w]) + w01 * bf_lo(pb[w]) +
                      w10 * bf_lo(pc[w]) + w11 * bf_lo(pd[w]);
          float pf1 = w00 * bf_hi(pa[w]) + w01 * bf_hi(pb[w]) +
                      w10 * bf_hi(pc[w]) + w11 * bf_hi(pd[w]);
          float lf0 = (w < 2) ? (wl0 * q0[2 * w] + wl * q1[2 * w])
                              : (wl0 * (&e0b.x)[2 * w - 4] + wl * (&e1b.x)[2 * w - 4]);
          float lf1 = (w < 2) ? (wl0 * q0[2 * w + 1] + wl * q1[2 * w + 1])
                              : (wl0 * (&e0b.x)[2 * w - 3] + wl * (&e1b.x)[2 * w - 3]);
          feats[c0 + 0] += pf0 * lf0;
          feats[c0 + 1] += pf1 * lf1;
        }
      }
    } else {
#pragma unroll 4
      for (int c = 0; c < NC; ++c) {
        const float* pl = planes_f32 + (size_t)(q * NC + c) * RES * RES;
        float a  = pl[y0 * RES + x0], b = pl[y0 * RES + x1];
        float c2 = pl[y1 * RES + x0], d = pl[y1 * RES + x1];
        const float* ln = lines_f32 + (size_t)(q * NC + c) * RES;
        float lf = ln[l0] * wl0 + ln[l1] * wl;
        feats[c] += (w00 * a + w01 * b + w10 * c2 + w11 * d) * lf;
      }
    }
  }

  // pfeat: _sample1d(params_grid [3,3], t)
  {
    float it = (t + 1.0f) * 0.5f * 2.0f;
    float ft = floorf(it);
    float wt = it - ft;
    int t0 = (int)ft; t0 = t0 < 0 ? 0 : (t0 > 2 ? 2 : t0);
    int t1 = (t0 + 1 > 2) ? 2 : t0 + 1;
    feats[16] = spg[0 + t0] * (1.0f - wt) + spg[0 + t1] * wt;
    feats[17] = spg[3 + t0] * (1.0f - wt) + spg[3 + t1] * wt;
    feats[18] = spg[6 + t0] * (1.0f - wt) + spg[6 + t1] * wt;
    feats[19] = 0.0f;
  }

  // 19->32 matmul (pad to 20, float4 broadcast reads from LDS)
  float res[32];
#pragma unroll
  for (int o = 0; o < 32; ++o) {
    const float4* wr = (const float4*)(sW + o * 20);
    float acc = 0.0f;
#pragma unroll
    for (int k = 0; k < 5; ++k) {
      float4 wv = wr[k];
      acc += feats[4 * k + 0] * wv.x + feats[4 * k + 1] * wv.y +
             feats[4 * k + 2] * wv.z + feats[4 * k + 3] * wv.w;
    }
    res[o] = acc;
  }

  // stage to LDS with rotate-swizzle so both phases are conflict-free,
  // then write fully-coalesced float4s (full 128B lines per instruction).
#pragma unroll
  for (int o = 0; o < 32; ++o)
    st[tid * 32 + ((o + tid) & 31)] = res[o];
  __syncthreads();

  size_t gbase = (size_t)blockIdx.x * 8192;
  size_t total = (size_t)N * 32;
#pragma unroll
  for (int k = 0; k < 8; ++k) {
    int idx = tid + k * 256;
    int j   = idx * 4;
    int pq  = j >> 5;
    f32x4 v;
    v.x = st[pq * 32 + (((j & 31) + 0 + pq) & 31)];
    v.y = st[pq * 32 + (((j & 31) + 1 + pq) & 31)];
    v.z = st[pq * 32 + (((j & 31) + 2 + pq) & 31)];
    v.w = st[pq * 32 + (((j & 31) + 3 + pq) & 31)];
    if (gbase + j + 4 <= total) {
      nt_store4(out + gbase + j, v);
    }
  }
}

extern "C" void kernel_launch(void* const* d_in, const int* in_sizes, int n_in,
                              void* d_out, int out_size, void* d_ws, size_t ws_size,
                              hipStream_t stream)
{
  const float* pts    = (const float*)d_in[0];
  const float* ts     = (const float*)d_in[1];
  const float* planes = (const float*)d_in[2];
  const float* lines  = (const float*)d_in[3];
  const float* pg     = (const float*)d_in[4];
  const float* W      = (const float*)d_in[5];
  float* out = (float*)d_out;
  int N = in_sizes[0] / 3;

  size_t planesTb_bytes = (size_t)NPLANES * RES * RES * NC * sizeof(__hip_bfloat16);
  size_t linesT_bytes   = (size_t)NPLANES * RES * NC * sizeof(float);
  int blocksMain = (N + 255) / 256;

  if (ws_size >= planesTb_bytes + linesT_bytes) {
    __hip_bfloat16* planesTb = (__hip_bfloat16*)d_ws;
    float* linesT = (float*)((char*)d_ws + planesTb_bytes);
    transpose_planes_k<<<NPLANES * RES * (RES / 64), 256, 0, stream>>>(planes, planesTb);
    transpose_lines_k<<<(NPLANES * RES * NC + 255) / 256, 256, 0, stream>>>(lines, linesT);
    visnerf_main_k<true><<<blocksMain, 256, 0, stream>>>(
        pts, ts, planesTb, linesT, nullptr, nullptr, pg, W, out, N);
  } else {
    visnerf_main_k<false><<<blocksMain, 256, 0, stream>>>(
        pts, ts, nullptr, nullptr, planes, lines, pg, W, out, N);
  }
}